// Round 1
// baseline (127599.060 us; speedup 1.0000x reference)
//
#include <hip/hip_runtime.h>
#include <cstdint>

typedef unsigned int uint;
typedef unsigned short ushort;
typedef unsigned char uchar;

#define TSTEPS 8192
#define HIDDEN 2048
#define EMBDIM 512

// ---------- helpers ----------
__device__ __forceinline__ ushort f2bf(float f) {
  uint u = __float_as_uint(f);
  uint r = u + 0x7fffu + ((u >> 16) & 1u);   // RNE
  return (ushort)(r >> 16);
}
__device__ __forceinline__ float bf2f(ushort h) {
  return __uint_as_float(((uint)h) << 16);
}
__device__ __forceinline__ uint pk2(float a, float b) {
  return (uint)f2bf(a) | ((uint)f2bf(b) << 16);
}

typedef __bf16 bf16x2 __attribute__((ext_vector_type(2)));

__device__ __forceinline__ float dot2bf(uint a, uint b, float acc) {
#if __has_builtin(__builtin_amdgcn_fdot2_f32_bf16)
  return __builtin_amdgcn_fdot2_f32_bf16(__builtin_bit_cast(bf16x2, a),
                                         __builtin_bit_cast(bf16x2, b), acc, false);
#else
  acc += bf2f((ushort)(a & 0xffffu)) * bf2f((ushort)(b & 0xffffu));
  acc += bf2f((ushort)(a >> 16))     * bf2f((ushort)(b >> 16));
  return acc;
#endif
}

__device__ __forceinline__ float sigm(float x)   { return 1.0f / (1.0f + __expf(-x)); }
__device__ __forceinline__ float tanh_f(float x) { return 1.0f - 2.0f / (__expf(2.0f * x) + 1.0f); }

// ---------- kernel A: G_x[char][row] = b_all[row] + W_all[row, :512] @ emb[char] ----------
// block k (0..255) computes its CU's 32 rows for all 256 chars.
// row mapping: lr = gate*8 + jj  (gate: 0=f,1=i,2=c~,3=o), global row in gate matrix = k*8+jj
__global__ __launch_bounds__(256) void gx_kernel(
    const float* __restrict__ emb,
    const float* __restrict__ Wf, const float* __restrict__ bf_,
    const float* __restrict__ Wi, const float* __restrict__ bi_,
    const float* __restrict__ Wc, const float* __restrict__ bc_,
    const float* __restrict__ Wo, const float* __restrict__ bo_,
    ushort* __restrict__ gxg)
{
  __shared__ uint4 Wsh4[32 * 64];    // 32 rows x 512 bf16 = 32 KB
  __shared__ uint4 Esh4[16 * 65];    // 16 chars x 520 bf16 (pad) = 16.25 KB
  ushort* W_sh = (ushort*)Wsh4;
  ushort* e_sh = (ushort*)Esh4;
  const int tid = threadIdx.x, bid = blockIdx.x;

  for (int idx = tid; idx < 32 * 512; idx += 256) {
    int lr = idx >> 9, e = idx & 511;
    int gate = lr >> 3, jj = lr & 7;
    const float* Wg = (gate == 0) ? Wf : (gate == 1) ? Wi : (gate == 2) ? Wc : Wo;
    W_sh[lr * 512 + e] = f2bf(Wg[(size_t)(bid * 8 + jj) * 2560 + e]);
  }
  const int lr = tid >> 3, cp = tid & 7;
  const int gate = lr >> 3, jj = lr & 7;
  const float* bg = (gate == 0) ? bf_ : (gate == 1) ? bi_ : (gate == 2) ? bc_ : bo_;
  const float bias = bg[bid * 8 + jj];

  for (int ct = 0; ct < 16; ++ct) {
    __syncthreads();
    for (int idx = tid; idx < 16 * 512; idx += 256) {
      int cc = idx >> 9, e = idx & 511;
      e_sh[cc * 520 + e] = f2bf(emb[(size_t)(ct * 16 + cc) * 512 + e]);
    }
    __syncthreads();
    const uint4* wrow = Wsh4 + lr * 64;
    const uint4* ea = Esh4 + (cp * 2) * 65;
    const uint4* eb = Esh4 + (cp * 2 + 1) * 65;
    float a0 = 0.f, a1 = 0.f;
#pragma unroll 4
    for (int e8 = 0; e8 < 64; ++e8) {
      uint4 wv = wrow[e8], va = ea[e8], vb = eb[e8];
      a0 = dot2bf(wv.x, va.x, a0); a0 = dot2bf(wv.y, va.y, a0);
      a0 = dot2bf(wv.z, va.z, a0); a0 = dot2bf(wv.w, va.w, a0);
      a1 = dot2bf(wv.x, vb.x, a1); a1 = dot2bf(wv.y, vb.y, a1);
      a1 = dot2bf(wv.z, vb.z, a1); a1 = dot2bf(wv.w, vb.w, a1);
    }
    int ch0 = ct * 16 + cp * 2;
    gxg[(size_t)bid * 8192 + ch0 * 32 + lr]       = f2bf(a0 + bias);
    gxg[(size_t)bid * 8192 + (ch0 + 1) * 32 + lr] = f2bf(a1 + bias);
  }
}

// ---------- kernel A2: W_y -> bf16 ----------
__global__ __launch_bounds__(256) void wyb_kernel(const float* __restrict__ Wy,
                                                  ushort* __restrict__ Wyb)
{
  int i = blockIdx.x * 256 + threadIdx.x;   // 131072 float4 = 524288 elems
  if (i < 131072) {
    float4 v = ((const float4*)Wy)[i];
    uint2 o; o.x = pk2(v.x, v.y); o.y = pk2(v.z, v.w);
    ((uint2*)Wyb)[i] = o;
  }
}

// ---------- kernel B: persistent sequential LSTM ----------
// 256 blocks x 1024 threads. Block k owns h elements [8k, 8k+8) and their 4 gate rows
// (32 rows x 2048 cols of W_h, bf16, register-resident: 32 VGPR/lane).
// Wave w handles rows lr0=2w, 2w+1; lane g covers col-chunks {i*64+g}*8.
__global__ __launch_bounds__(1024, 4) void lstm_kernel(
    const int* __restrict__ seq,
    const float* __restrict__ Wf, const float* __restrict__ Wi,
    const float* __restrict__ Wc, const float* __restrict__ Wo,
    const ushort* __restrict__ gxg,
    uint* __restrict__ hist,   // [T][1024] dwords (bf16 pairs)
    uint* __restrict__ hbuf,   // [2][1024] dwords (bf16 pairs)
    uint* __restrict__ cnt,    // 8 group counters, 128B apart
    uint* __restrict__ root,
    float* __restrict__ out_h, float* __restrict__ out_c)
{
  __shared__ uint4 hsh4[256];      // h_{t-1}: 2048 bf16 = 4 KB
  __shared__ uint4 gxsh4[1024];    // G_x slice: 256 chars x 32 rows bf16 = 16 KB
  __shared__ uchar seq_sh[TSTEPS]; // 8 KB
  __shared__ float g_sh[32];
  __shared__ float c_sh[8];
  __shared__ uint  step_flag;

  const int tid = threadIdx.x, bid = blockIdx.x;
  const int w = tid >> 6, g = tid & 63;

  // W_h into registers (bf16 packed pairs)
  const int lr0 = 2 * w;
  const int gate = lr0 >> 3, jj0 = lr0 & 7;
  const float* Wg = (gate == 0) ? Wf : (gate == 1) ? Wi : (gate == 2) ? Wc : Wo;
  const float* W0 = Wg + (size_t)(bid * 8 + jj0) * 2560 + 512;
  const float* W1 = W0 + 2560;
  uint4 wa[4], wb[4];
#pragma unroll
  for (int i = 0; i < 4; ++i) {
    int col = (i * 64 + g) * 8;
    float4 x0 = *(const float4*)(W0 + col);
    float4 x1 = *(const float4*)(W0 + col + 4);
    wa[i] = make_uint4(pk2(x0.x, x0.y), pk2(x0.z, x0.w), pk2(x1.x, x1.y), pk2(x1.z, x1.w));
    float4 y0 = *(const float4*)(W1 + col);
    float4 y1 = *(const float4*)(W1 + col + 4);
    wb[i] = make_uint4(pk2(y0.x, y0.y), pk2(y0.z, y0.w), pk2(y1.x, y1.y), pk2(y1.z, y1.w));
  }

  // stage G_x slice + seq, zero h/c
  gxsh4[tid] = ((const uint4*)(gxg + (size_t)bid * 8192))[tid];
  {
    int4 v0 = ((const int4*)seq)[tid];
    int4 v1 = ((const int4*)seq)[tid + 1024];
    seq_sh[4 * tid + 0] = (uchar)v0.x; seq_sh[4 * tid + 1] = (uchar)v0.y;
    seq_sh[4 * tid + 2] = (uchar)v0.z; seq_sh[4 * tid + 3] = (uchar)v0.w;
    seq_sh[4096 + 4 * tid + 0] = (uchar)v1.x; seq_sh[4096 + 4 * tid + 1] = (uchar)v1.y;
    seq_sh[4096 + 4 * tid + 2] = (uchar)v1.z; seq_sh[4096 + 4 * tid + 3] = (uchar)v1.w;
  }
  if (tid < 256) hsh4[tid] = make_uint4(0u, 0u, 0u, 0u);
  if (tid < 8)  c_sh[tid] = 0.f;
  if (tid == 0) step_flag = 0u;
  __syncthreads();

  const ushort* gx_sh = (const ushort*)gxsh4;
  uint* mycnt = cnt + (bid & 7) * 32;

  for (int t = 0; t < TSTEPS; ++t) {
    // ---- phase A: partial dots over h_{t-1} ----
    float a0 = 0.f, a1 = 0.f;
#pragma unroll
    for (int i = 0; i < 4; ++i) {
      uint4 hv = hsh4[i * 64 + g];
      a0 = dot2bf(wa[i].x, hv.x, a0); a0 = dot2bf(wa[i].y, hv.y, a0);
      a0 = dot2bf(wa[i].z, hv.z, a0); a0 = dot2bf(wa[i].w, hv.w, a0);
      a1 = dot2bf(wb[i].x, hv.x, a1); a1 = dot2bf(wb[i].y, hv.y, a1);
      a1 = dot2bf(wb[i].z, hv.z, a1); a1 = dot2bf(wb[i].w, hv.w, a1);
    }
    float s0 = __shfl_xor(a0, 32);
    float s1 = __shfl_xor(a1, 32);
    float a = (g < 32) ? (a0 + s0) : (a1 + s1);
    a += __shfl_xor(a, 16); a += __shfl_xor(a, 8);
    a += __shfl_xor(a, 4);  a += __shfl_xor(a, 2); a += __shfl_xor(a, 1);
    if ((g & 31) == 0) g_sh[lr0 + (g >> 5)] = a;
    __syncthreads();   // #1: g ready

    if (w == 0) {
      if (g < 8) {
        const int ch = (int)seq_sh[t];
        const ushort* gx = gx_sh + ch * 32;
        float vf = g_sh[g]      + bf2f(gx[g]);
        float vi = g_sh[8 + g]  + bf2f(gx[8 + g]);
        float vc = g_sh[16 + g] + bf2f(gx[16 + g]);
        float vo = g_sh[24 + g] + bf2f(gx[24 + g]);
        float f_ = sigm(vf), i_ = sigm(vi), ct_ = tanh_f(vc), o_ = sigm(vo);
        float cn = f_ * c_sh[g] + i_ * ct_;
        c_sh[g] = cn;
        float h = o_ * tanh_f(cn);
        uint hb = (uint)f2bf(h);
        uint nb = __shfl_down(hb, 1);
        if ((g & 1) == 0) {
          uint dw = hb | (nb << 16);
          int di = bid * 4 + (g >> 1);
          __hip_atomic_store(hbuf + (t & 1) * 1024 + di, dw,
                             __ATOMIC_RELAXED, __HIP_MEMORY_SCOPE_AGENT);
          __builtin_nontemporal_store(dw, hist + (size_t)t * 1024 + di);
        }
        if (t == TSTEPS - 1) { out_h[bid * 8 + g] = h; out_c[bid * 8 + g] = cn; }
      }
      if (t < TSTEPS - 1) {
        if (g == 0) {
          uint old = __hip_atomic_fetch_add(mycnt, 1u, __ATOMIC_ACQ_REL, __HIP_MEMORY_SCOPE_AGENT);
          if (old == 32u * (uint)(t + 1) - 1u)
            __hip_atomic_fetch_add(root, 1u, __ATOMIC_RELEASE, __HIP_MEMORY_SCOPE_AGENT);
          const uint tgt = 8u * (uint)(t + 1);
          while (__hip_atomic_load(root, __ATOMIC_RELAXED, __HIP_MEMORY_SCOPE_AGENT) < tgt) { }
        }
        (void)__hip_atomic_load(root, __ATOMIC_ACQUIRE, __HIP_MEMORY_SCOPE_AGENT); // inv
        if (g == 0) *(volatile uint*)&step_flag = (uint)(t + 1);
        uint4 v = ((const uint4*)(hbuf + (t & 1) * 1024))[g];
        hsh4[g] = v;
      }
    } else if (w < 4) {
      if (t < TSTEPS - 1) {
        if (g == 0) {
          while (*(volatile uint*)&step_flag < (uint)(t + 1)) { }
        }
        (void)__hip_atomic_load(root, __ATOMIC_ACQUIRE, __HIP_MEMORY_SCOPE_AGENT); // inv
        uint4 v = ((const uint4*)(hbuf + (t & 1) * 1024))[w * 64 + g];
        hsh4[w * 64 + g] = v;
      }
    }
    __syncthreads();   // #3: h_t staged in LDS
  }
}

// ---------- kernel C: y = hist @ W_y^T + b_y ----------
// block: 16 t-rows x 256 n. thread: 4t x 4n.
__global__ __launch_bounds__(256) void y_kernel(
    const ushort* __restrict__ hist,
    const ushort* __restrict__ Wyb,
    const float* __restrict__ by,
    float* __restrict__ y)
{
  __shared__ uint4 hsh4[4096];   // 16 x 2048 bf16 = 64 KB
  const int tid = threadIdx.x, bid = blockIdx.x;
  const int t0 = bid * 16;
  const uint4* src = (const uint4*)(hist + (size_t)t0 * 2048);
  for (int i = tid; i < 4096; i += 256) hsh4[i] = src[i];
  __syncthreads();
  const int a = tid >> 6, b = tid & 63;
  const int n0 = b * 4;
  float acc[4][4];
#pragma unroll
  for (int i = 0; i < 4; ++i)
#pragma unroll
    for (int j = 0; j < 4; ++j) acc[i][j] = 0.f;
  const uint4* wy = (const uint4*)Wyb;
  for (int k8 = 0; k8 < 256; ++k8) {
    uint4 hv[4];
#pragma unroll
    for (int ti = 0; ti < 4; ++ti) hv[ti] = hsh4[(a + ti * 4) * 256 + k8];
#pragma unroll
    for (int nj = 0; nj < 4; ++nj) {
      uint4 wv = wy[(size_t)(n0 + nj) * 256 + k8];
#pragma unroll
      for (int ti = 0; ti < 4; ++ti) {
        acc[ti][nj] = dot2bf(hv[ti].x, wv.x, acc[ti][nj]);
        acc[ti][nj] = dot2bf(hv[ti].y, wv.y, acc[ti][nj]);
        acc[ti][nj] = dot2bf(hv[ti].z, wv.z, acc[ti][nj]);
        acc[ti][nj] = dot2bf(hv[ti].w, wv.w, acc[ti][nj]);
      }
    }
  }
  float4 bv = *(const float4*)(by + n0);
#pragma unroll
  for (int ti = 0; ti < 4; ++ti) {
    int t = t0 + a + ti * 4;
    float4 o;
    o.x = acc[ti][0] + bv.x; o.y = acc[ti][1] + bv.y;
    o.z = acc[ti][2] + bv.z; o.w = acc[ti][3] + bv.w;
    *(float4*)(y + (size_t)t * 256 + n0) = o;
  }
}

// ---------- launcher ----------
extern "C" void kernel_launch(void* const* d_in, const int* in_sizes, int n_in,
                              void* d_out, int out_size, void* d_ws, size_t ws_size,
                              hipStream_t stream)
{
  const int*   seq = (const int*)d_in[0];
  const float* emb = (const float*)d_in[1];
  const float* Wf  = (const float*)d_in[2];
  const float* bf_ = (const float*)d_in[3];
  const float* Wi  = (const float*)d_in[4];
  const float* bi_ = (const float*)d_in[5];
  const float* Wo  = (const float*)d_in[6];
  const float* bo_ = (const float*)d_in[7];
  const float* Wc  = (const float*)d_in[8];
  const float* bc_ = (const float*)d_in[9];
  const float* Wy  = (const float*)d_in[10];
  const float* by  = (const float*)d_in[11];

  // ws layout
  const size_t OFF_GXG  = 0;                    // 4 MB   (256*256*32 bf16)
  const size_t OFF_HIST = 4194304;              // 32 MB  (8192*2048 bf16)
  const size_t OFF_HBUF = OFF_HIST + 33554432;  // 8 KB
  const size_t OFF_WYB  = OFF_HBUF + 8192;      // 1 MB
  const size_t OFF_CTR  = OFF_WYB + 1048576;    // 4 KB
  const size_t NEEDED   = OFF_CTR + 4096;
  if (ws_size < NEEDED) return;  // signals via untouched output

  char* ws = (char*)d_ws;
  ushort* gxg  = (ushort*)(ws + OFF_GXG);
  ushort* hist = (ushort*)(ws + OFF_HIST);
  uint*   hbuf = (uint*)  (ws + OFF_HBUF);
  ushort* Wyb  = (ushort*)(ws + OFF_WYB);
  uint*   ctr  = (uint*)  (ws + OFF_CTR);

  float* yout  = (float*)d_out;
  float* out_h = yout + (size_t)TSTEPS * 256;
  float* out_c = out_h + HIDDEN;

  hipMemsetAsync(ctr, 0, 4096, stream);
  hipLaunchKernelGGL(gx_kernel, dim3(256), dim3(256), 0, stream,
                     emb, Wf, bf_, Wi, bi_, Wc, bc_, Wo, bo_, gxg);
  hipLaunchKernelGGL(wyb_kernel, dim3(512), dim3(256), 0, stream, Wy, Wyb);
  hipLaunchKernelGGL(lstm_kernel, dim3(256), dim3(1024), 0, stream,
                     seq, Wf, Wi, Wc, Wo, gxg, (uint*)hist, hbuf,
                     ctr, ctr + 256, out_h, out_c);
  hipLaunchKernelGGL(y_kernel, dim3(512), dim3(256), 0, stream,
                     hist, Wyb, by, yout);
}

// Round 2
// 21351.837 us; speedup vs baseline: 5.9760x; 5.9760x over previous
//
#include <hip/hip_runtime.h>
#include <cstdint>

typedef unsigned int uint;
typedef unsigned short ushort;
typedef unsigned char uchar;
typedef unsigned long long u64;

#define TSTEPS 8192
#define HIDDEN 2048
#define EMBDIM 512

// ---------- helpers ----------
__device__ __forceinline__ ushort f2bf(float f) {
  uint u = __float_as_uint(f);
  uint r = u + 0x7fffu + ((u >> 16) & 1u);   // RNE
  return (ushort)(r >> 16);
}
__device__ __forceinline__ float bf2f(ushort h) {
  return __uint_as_float(((uint)h) << 16);
}
__device__ __forceinline__ uint pk2(float a, float b) {
  return (uint)f2bf(a) | ((uint)f2bf(b) << 16);
}

typedef __bf16 bf16x2 __attribute__((ext_vector_type(2)));

__device__ __forceinline__ float dot2bf(uint a, uint b, float acc) {
#if __has_builtin(__builtin_amdgcn_fdot2_f32_bf16)
  return __builtin_amdgcn_fdot2_f32_bf16(__builtin_bit_cast(bf16x2, a),
                                         __builtin_bit_cast(bf16x2, b), acc, false);
#else
  acc += bf2f((ushort)(a & 0xffffu)) * bf2f((ushort)(b & 0xffffu));
  acc += bf2f((ushort)(a >> 16))     * bf2f((ushort)(b >> 16));
  return acc;
#endif
}

__device__ __forceinline__ float sigm(float x)   { return 1.0f / (1.0f + __expf(-x)); }
__device__ __forceinline__ float tanh_f(float x) { return 1.0f - 2.0f / (__expf(2.0f * x) + 1.0f); }

// ---------- kernel A: G_x[char][row] = b_all[row] + W_all[row, :512] @ emb[char] ----------
__global__ __launch_bounds__(256) void gx_kernel(
    const float* __restrict__ emb,
    const float* __restrict__ Wf, const float* __restrict__ bf_,
    const float* __restrict__ Wi, const float* __restrict__ bi_,
    const float* __restrict__ Wc, const float* __restrict__ bc_,
    const float* __restrict__ Wo, const float* __restrict__ bo_,
    ushort* __restrict__ gxg)
{
  __shared__ uint4 Wsh4[32 * 64];    // 32 rows x 512 bf16 = 32 KB
  __shared__ uint4 Esh4[16 * 65];    // 16 chars x 520 bf16 (pad) = 16.25 KB
  ushort* W_sh = (ushort*)Wsh4;
  ushort* e_sh = (ushort*)Esh4;
  const int tid = threadIdx.x, bid = blockIdx.x;

  for (int idx = tid; idx < 32 * 512; idx += 256) {
    int lr = idx >> 9, e = idx & 511;
    int gate = lr >> 3, jj = lr & 7;
    const float* Wg = (gate == 0) ? Wf : (gate == 1) ? Wi : (gate == 2) ? Wc : Wo;
    W_sh[lr * 512 + e] = f2bf(Wg[(size_t)(bid * 8 + jj) * 2560 + e]);
  }
  const int lr = tid >> 3, cp = tid & 7;
  const int gate = lr >> 3, jj = lr & 7;
  const float* bg = (gate == 0) ? bf_ : (gate == 1) ? bi_ : (gate == 2) ? bc_ : bo_;
  const float bias = bg[bid * 8 + jj];

  for (int ct = 0; ct < 16; ++ct) {
    __syncthreads();
    for (int idx = tid; idx < 16 * 512; idx += 256) {
      int cc = idx >> 9, e = idx & 511;
      e_sh[cc * 520 + e] = f2bf(emb[(size_t)(ct * 16 + cc) * 512 + e]);
    }
    __syncthreads();
    const uint4* wrow = Wsh4 + lr * 64;
    const uint4* ea = Esh4 + (cp * 2) * 65;
    const uint4* eb = Esh4 + (cp * 2 + 1) * 65;
    float a0 = 0.f, a1 = 0.f;
#pragma unroll 4
    for (int e8 = 0; e8 < 64; ++e8) {
      uint4 wv = wrow[e8], va = ea[e8], vb = eb[e8];
      a0 = dot2bf(wv.x, va.x, a0); a0 = dot2bf(wv.y, va.y, a0);
      a0 = dot2bf(wv.z, va.z, a0); a0 = dot2bf(wv.w, va.w, a0);
      a1 = dot2bf(wv.x, vb.x, a1); a1 = dot2bf(wv.y, vb.y, a1);
      a1 = dot2bf(wv.z, vb.z, a1); a1 = dot2bf(wv.w, vb.w, a1);
    }
    int ch0 = ct * 16 + cp * 2;
    gxg[(size_t)bid * 8192 + ch0 * 32 + lr]       = f2bf(a0 + bias);
    gxg[(size_t)bid * 8192 + (ch0 + 1) * 32 + lr] = f2bf(a1 + bias);
  }
}

// ---------- kernel A2: W_y -> bf16 ----------
__global__ __launch_bounds__(256) void wyb_kernel(const float* __restrict__ Wy,
                                                  ushort* __restrict__ Wyb)
{
  int i = blockIdx.x * 256 + threadIdx.x;
  if (i < 131072) {
    float4 v = ((const float4*)Wy)[i];
    uint2 o; o.x = pk2(v.x, v.y); o.y = pk2(v.z, v.w);
    ((uint2*)Wyb)[i] = o;
  }
}

// ---------- kernel B: persistent sequential LSTM ----------
// 256 blocks x 1024 threads, 1 block/CU. Block k owns h[8k,8k+8) and its 32 gate
// rows of W_h register-resident. h exchange: self-validating 8B slots
// (bf16 pair | step tag) via relaxed agent atomics — no barrier, no fences.
__global__ __launch_bounds__(1024, 4) void lstm_kernel(
    const int* __restrict__ seq,
    const float* __restrict__ Wf, const float* __restrict__ Wi,
    const float* __restrict__ Wc, const float* __restrict__ Wo,
    const ushort* __restrict__ gxg,
    uint* __restrict__ hist,   // [T][1024] dwords (bf16 pairs)
    u64* __restrict__ hbuf,    // [2][1024] slots: (tag<<32)|hpair
    float* __restrict__ out_h, float* __restrict__ out_c)
{
  __shared__ uint4 hsh4[256];      // h_{t-1}: 2048 bf16 = 4 KB
  __shared__ uint4 gxsh4[1024];    // G_x slice: 256 chars x 32 rows bf16 = 16 KB
  __shared__ uchar seq_sh[TSTEPS]; // 8 KB
  __shared__ float g_sh[32];
  __shared__ float c_sh[8];

  const int tid = threadIdx.x, bid = blockIdx.x;
  const int w = tid >> 6, g = tid & 63;

  // W_h into registers (bf16 packed pairs): wave w rows {2w, 2w+1}
  const int lr0 = 2 * w;
  const int gate = lr0 >> 3, jj0 = lr0 & 7;
  const float* Wg = (gate == 0) ? Wf : (gate == 1) ? Wi : (gate == 2) ? Wc : Wo;
  const float* W0 = Wg + (size_t)(bid * 8 + jj0) * 2560 + 512;
  const float* W1 = W0 + 2560;
  uint4 wa[4], wb[4];
#pragma unroll
  for (int i = 0; i < 4; ++i) {
    int col = (i * 64 + g) * 8;
    float4 x0 = *(const float4*)(W0 + col);
    float4 x1 = *(const float4*)(W0 + col + 4);
    wa[i] = make_uint4(pk2(x0.x, x0.y), pk2(x0.z, x0.w), pk2(x1.x, x1.y), pk2(x1.z, x1.w));
    float4 y0 = *(const float4*)(W1 + col);
    float4 y1 = *(const float4*)(W1 + col + 4);
    wb[i] = make_uint4(pk2(y0.x, y0.y), pk2(y0.z, y0.w), pk2(y1.x, y1.y), pk2(y1.z, y1.w));
  }

  // stage G_x slice + seq, zero h/c
  gxsh4[tid] = ((const uint4*)(gxg + (size_t)bid * 8192))[tid];
  {
    int4 v0 = ((const int4*)seq)[tid];
    int4 v1 = ((const int4*)seq)[tid + 1024];
    seq_sh[4 * tid + 0] = (uchar)v0.x; seq_sh[4 * tid + 1] = (uchar)v0.y;
    seq_sh[4 * tid + 2] = (uchar)v0.z; seq_sh[4 * tid + 3] = (uchar)v0.w;
    seq_sh[4096 + 4 * tid + 0] = (uchar)v1.x; seq_sh[4096 + 4 * tid + 1] = (uchar)v1.y;
    seq_sh[4096 + 4 * tid + 2] = (uchar)v1.z; seq_sh[4096 + 4 * tid + 3] = (uchar)v1.w;
  }
  if (tid < 256) hsh4[tid] = make_uint4(0u, 0u, 0u, 0u);
  if (tid < 8)  c_sh[tid] = 0.f;
  __syncthreads();

  const ushort* gx_sh = (const ushort*)gxsh4;
  uint* hsh_dw = (uint*)hsh4;

  for (int t = 0; t < TSTEPS; ++t) {
    // ---- phase A: partial dots over h_{t-1} (all 16 waves) ----
    float a0 = 0.f, a1 = 0.f;
#pragma unroll
    for (int i = 0; i < 4; ++i) {
      uint4 hv = hsh4[i * 64 + g];
      a0 = dot2bf(wa[i].x, hv.x, a0); a0 = dot2bf(wa[i].y, hv.y, a0);
      a0 = dot2bf(wa[i].z, hv.z, a0); a0 = dot2bf(wa[i].w, hv.w, a0);
      a1 = dot2bf(wb[i].x, hv.x, a1); a1 = dot2bf(wb[i].y, hv.y, a1);
      a1 = dot2bf(wb[i].z, hv.z, a1); a1 = dot2bf(wb[i].w, hv.w, a1);
    }
    float s0 = __shfl_xor(a0, 32);
    float s1 = __shfl_xor(a1, 32);
    float a = (g < 32) ? (a0 + s0) : (a1 + s1);
    a += __shfl_xor(a, 16); a += __shfl_xor(a, 8);
    a += __shfl_xor(a, 4);  a += __shfl_xor(a, 2); a += __shfl_xor(a, 1);
    if ((g & 31) == 0) g_sh[lr0 + (g >> 5)] = a;
    __syncthreads();   // #1: g_sh ready

    // ---- gates: wave 0, lanes 0..7 (h element j = g) ----
    if (w == 0 && g < 8) {
      const int ch = (int)seq_sh[t];
      const ushort* gx = gx_sh + ch * 32;
      float vf = g_sh[g]      + bf2f(gx[g]);
      float vi = g_sh[8 + g]  + bf2f(gx[8 + g]);
      float vc = g_sh[16 + g] + bf2f(gx[16 + g]);
      float vo = g_sh[24 + g] + bf2f(gx[24 + g]);
      float f_ = sigm(vf), i_ = sigm(vi), ct_ = tanh_f(vc), o_ = sigm(vo);
      float cn = f_ * c_sh[g] + i_ * ct_;
      c_sh[g] = cn;
      float h = o_ * tanh_f(cn);
      uint hb = (uint)f2bf(h);
      uint nb = __shfl_down(hb, 1);
      if ((g & 1) == 0) {
        uint dw = hb | (nb << 16);
        int di = bid * 4 + (g >> 1);
        u64 v = (u64)dw | ((u64)(uint)(t + 1) << 32);
        __hip_atomic_store(hbuf + (size_t)(t & 1) * 1024 + di, v,
                           __ATOMIC_RELAXED, __HIP_MEMORY_SCOPE_AGENT);
        __builtin_nontemporal_store(dw, hist + (size_t)t * 1024 + di);
      }
      if (t == TSTEPS - 1) { out_h[bid * 8 + g] = h; out_c[bid * 8 + g] = cn; }
    }

    // ---- exchange: every thread polls its own 8B slot (parallel RTs) ----
    if (t < TSTEPS - 1) {
      const u64 want = (u64)(uint)(t + 1);
      const u64* slot = hbuf + (size_t)(t & 1) * 1024 + tid;
      u64 v;
      do {
        v = __hip_atomic_load(slot, __ATOMIC_RELAXED, __HIP_MEMORY_SCOPE_AGENT);
      } while ((v >> 32) != want);
      hsh_dw[tid] = (uint)v;
    }
    __syncthreads();   // #2: h_t staged in LDS
  }
}

// ---------- kernel C: y = hist @ W_y^T + b_y ----------
__global__ __launch_bounds__(256) void y_kernel(
    const ushort* __restrict__ hist,
    const ushort* __restrict__ Wyb,
    const float* __restrict__ by,
    float* __restrict__ y)
{
  __shared__ uint4 hsh4[4096];   // 16 x 2048 bf16 = 64 KB
  const int tid = threadIdx.x, bid = blockIdx.x;
  const int t0 = bid * 16;
  const uint4* src = (const uint4*)(hist + (size_t)t0 * 2048);
  for (int i = tid; i < 4096; i += 256) hsh4[i] = src[i];
  __syncthreads();
  const int a = tid >> 6, b = tid & 63;
  const int n0 = b * 4;
  float acc[4][4];
#pragma unroll
  for (int i = 0; i < 4; ++i)
#pragma unroll
    for (int j = 0; j < 4; ++j) acc[i][j] = 0.f;
  const uint4* wy = (const uint4*)Wyb;
  for (int k8 = 0; k8 < 256; ++k8) {
    uint4 hv[4];
#pragma unroll
    for (int ti = 0; ti < 4; ++ti) hv[ti] = hsh4[(a + ti * 4) * 256 + k8];
#pragma unroll
    for (int nj = 0; nj < 4; ++nj) {
      uint4 wv = wy[(size_t)(n0 + nj) * 256 + k8];
#pragma unroll
      for (int ti = 0; ti < 4; ++ti) {
        acc[ti][nj] = dot2bf(hv[ti].x, wv.x, acc[ti][nj]);
        acc[ti][nj] = dot2bf(hv[ti].y, wv.y, acc[ti][nj]);
        acc[ti][nj] = dot2bf(hv[ti].z, wv.z, acc[ti][nj]);
        acc[ti][nj] = dot2bf(hv[ti].w, wv.w, acc[ti][nj]);
      }
    }
  }
  float4 bv = *(const float4*)(by + n0);
#pragma unroll
  for (int ti = 0; ti < 4; ++ti) {
    int t = t0 + a + ti * 4;
    float4 o;
    o.x = acc[ti][0] + bv.x; o.y = acc[ti][1] + bv.y;
    o.z = acc[ti][2] + bv.z; o.w = acc[ti][3] + bv.w;
    *(float4*)(y + (size_t)t * 256 + n0) = o;
  }
}

// ---------- launcher ----------
extern "C" void kernel_launch(void* const* d_in, const int* in_sizes, int n_in,
                              void* d_out, int out_size, void* d_ws, size_t ws_size,
                              hipStream_t stream)
{
  const int*   seq = (const int*)d_in[0];
  const float* emb = (const float*)d_in[1];
  const float* Wf  = (const float*)d_in[2];
  const float* bf_ = (const float*)d_in[3];
  const float* Wi  = (const float*)d_in[4];
  const float* bi_ = (const float*)d_in[5];
  const float* Wo  = (const float*)d_in[6];
  const float* bo_ = (const float*)d_in[7];
  const float* Wc  = (const float*)d_in[8];
  const float* bc_ = (const float*)d_in[9];
  const float* Wy  = (const float*)d_in[10];
  const float* by  = (const float*)d_in[11];

  // ws layout
  const size_t OFF_GXG  = 0;                    // 4 MB   (256*256*32 bf16)
  const size_t OFF_HIST = 4194304;              // 32 MB  (8192*2048 bf16)
  const size_t OFF_HBUF = OFF_HIST + 33554432;  // 16 KB  (2*1024 u64 slots)
  const size_t OFF_WYB  = OFF_HBUF + 16384;     // 1 MB
  const size_t NEEDED   = OFF_WYB + 1048576;
  if (ws_size < NEEDED) return;

  char* ws = (char*)d_ws;
  ushort* gxg  = (ushort*)(ws + OFF_GXG);
  ushort* hist = (ushort*)(ws + OFF_HIST);
  u64*    hbuf = (u64*)   (ws + OFF_HBUF);
  ushort* Wyb  = (ushort*)(ws + OFF_WYB);

  float* yout  = (float*)d_out;
  float* out_h = yout + (size_t)TSTEPS * 256;
  float* out_c = out_h + HIDDEN;

  hipLaunchKernelGGL(gx_kernel, dim3(256), dim3(256), 0, stream,
                     emb, Wf, bf_, Wi, bi_, Wc, bc_, Wo, bo_, gxg);
  hipLaunchKernelGGL(wyb_kernel, dim3(512), dim3(256), 0, stream, Wy, Wyb);
  hipLaunchKernelGGL(lstm_kernel, dim3(256), dim3(1024), 0, stream,
                     seq, Wf, Wi, Wc, Wo, gxg, (uint*)hist, hbuf,
                     out_h, out_c);
  hipLaunchKernelGGL(y_kernel, dim3(512), dim3(256), 0, stream,
                     hist, Wyb, by, yout);
}

// Round 3
// 15259.982 us; speedup vs baseline: 8.3617x; 1.3992x over previous
//
#include <hip/hip_runtime.h>
#include <cstdint>

typedef unsigned int uint;
typedef unsigned short ushort;
typedef unsigned char uchar;
typedef unsigned long long u64;
typedef long long i64;

#define TSTEPS 8192
#define HIDDEN 2048
#define EMBDIM 512

// calibration constants (shader cycles, ~2.4 GHz)
#define CAL_MARGIN 1800ull   // start polling ~0.75us before predicted arrival
#define CAL_MINPE  2400ull   // only calibrate once EMA is warmed & period sizable

// ---------- helpers ----------
__device__ __forceinline__ ushort f2bf(float f) {
  uint u = __float_as_uint(f);
  uint r = u + 0x7fffu + ((u >> 16) & 1u);   // RNE
  return (ushort)(r >> 16);
}
__device__ __forceinline__ float bf2f(ushort h) {
  return __uint_as_float(((uint)h) << 16);
}
__device__ __forceinline__ uint pk2(float a, float b) {
  return (uint)f2bf(a) | ((uint)f2bf(b) << 16);
}

typedef __bf16 bf16x2 __attribute__((ext_vector_type(2)));

__device__ __forceinline__ float dot2bf(uint a, uint b, float acc) {
#if __has_builtin(__builtin_amdgcn_fdot2_f32_bf16)
  return __builtin_amdgcn_fdot2_f32_bf16(__builtin_bit_cast(bf16x2, a),
                                         __builtin_bit_cast(bf16x2, b), acc, false);
#else
  acc += bf2f((ushort)(a & 0xffffu)) * bf2f((ushort)(b & 0xffffu));
  acc += bf2f((ushort)(a >> 16))     * bf2f((ushort)(b >> 16));
  return acc;
#endif
}

__device__ __forceinline__ float sigm(float x)   { return 1.0f / (1.0f + __expf(-x)); }
__device__ __forceinline__ float tanh_f(float x) { return 1.0f - 2.0f / (__expf(2.0f * x) + 1.0f); }

// ---------- kernel A: G_x[char][row] = b_all[row] + W_all[row, :512] @ emb[char] ----------
__global__ __launch_bounds__(256) void gx_kernel(
    const float* __restrict__ emb,
    const float* __restrict__ Wf, const float* __restrict__ bf_,
    const float* __restrict__ Wi, const float* __restrict__ bi_,
    const float* __restrict__ Wc, const float* __restrict__ bc_,
    const float* __restrict__ Wo, const float* __restrict__ bo_,
    ushort* __restrict__ gxg)
{
  __shared__ uint4 Wsh4[32 * 64];    // 32 rows x 512 bf16 = 32 KB
  __shared__ uint4 Esh4[16 * 65];    // 16 chars x 520 bf16 (pad) = 16.25 KB
  ushort* W_sh = (ushort*)Wsh4;
  ushort* e_sh = (ushort*)Esh4;
  const int tid = threadIdx.x, bid = blockIdx.x;

  for (int idx = tid; idx < 32 * 512; idx += 256) {
    int lr = idx >> 9, e = idx & 511;
    int gate = lr >> 3, jj = lr & 7;
    const float* Wg = (gate == 0) ? Wf : (gate == 1) ? Wi : (gate == 2) ? Wc : Wo;
    W_sh[lr * 512 + e] = f2bf(Wg[(size_t)(bid * 8 + jj) * 2560 + e]);
  }
  const int lr = tid >> 3, cp = tid & 7;
  const int gate = lr >> 3, jj = lr & 7;
  const float* bg = (gate == 0) ? bf_ : (gate == 1) ? bi_ : (gate == 2) ? bc_ : bo_;
  const float bias = bg[bid * 8 + jj];

  for (int ct = 0; ct < 16; ++ct) {
    __syncthreads();
    for (int idx = tid; idx < 16 * 512; idx += 256) {
      int cc = idx >> 9, e = idx & 511;
      e_sh[cc * 520 + e] = f2bf(emb[(size_t)(ct * 16 + cc) * 512 + e]);
    }
    __syncthreads();
    const uint4* wrow = Wsh4 + lr * 64;
    const uint4* ea = Esh4 + (cp * 2) * 65;
    const uint4* eb = Esh4 + (cp * 2 + 1) * 65;
    float a0 = 0.f, a1 = 0.f;
#pragma unroll 4
    for (int e8 = 0; e8 < 64; ++e8) {
      uint4 wv = wrow[e8], va = ea[e8], vb = eb[e8];
      a0 = dot2bf(wv.x, va.x, a0); a0 = dot2bf(wv.y, va.y, a0);
      a0 = dot2bf(wv.z, va.z, a0); a0 = dot2bf(wv.w, va.w, a0);
      a1 = dot2bf(wv.x, vb.x, a1); a1 = dot2bf(wv.y, vb.y, a1);
      a1 = dot2bf(wv.z, vb.z, a1); a1 = dot2bf(wv.w, vb.w, a1);
    }
    int ch0 = ct * 16 + cp * 2;
    gxg[(size_t)bid * 8192 + ch0 * 32 + lr]       = f2bf(a0 + bias);
    gxg[(size_t)bid * 8192 + (ch0 + 1) * 32 + lr] = f2bf(a1 + bias);
  }
}

// ---------- kernel A2: W_y -> bf16 ----------
__global__ __launch_bounds__(256) void wyb_kernel(const float* __restrict__ Wy,
                                                  ushort* __restrict__ Wyb)
{
  int i = blockIdx.x * 256 + threadIdx.x;
  if (i < 131072) {
    float4 v = ((const float4*)Wy)[i];
    uint2 o; o.x = pk2(v.x, v.y); o.y = pk2(v.z, v.w);
    ((uint2*)Wyb)[i] = o;
  }
}

// ---------- kernel B: persistent sequential LSTM ----------
// 256 blocks x 1024 threads, 1 block/CU. Block k owns h[8k,8k+8) and its 32 gate
// rows of W_h register-resident. h exchange: self-validating 8B slots
// (bf16 pair | step tag) via relaxed agent atomics. Calibrated rendezvous:
// each block predicts arrival (period EMA) and sleeps until ~margin before it,
// collapsing the poll storm to ~2-3 sweeps/step.
__global__ __launch_bounds__(1024, 4) void lstm_kernel(
    const int* __restrict__ seq,
    const float* __restrict__ Wf, const float* __restrict__ Wi,
    const float* __restrict__ Wc, const float* __restrict__ Wo,
    const ushort* __restrict__ gxg,
    uint* __restrict__ hist,   // [T][1024] dwords (bf16 pairs)
    u64* __restrict__ hbuf,    // [2][1024] slots: (tag<<32)|hpair
    float* __restrict__ out_h, float* __restrict__ out_c)
{
  __shared__ uint4 hsh4[256];      // h_{t-1}: 2048 bf16 = 4 KB
  __shared__ uint4 gxsh4[1024];    // G_x slice: 256 chars x 32 rows bf16 = 16 KB
  __shared__ uchar seq_sh[TSTEPS]; // 8 KB
  __shared__ float g_sh[32];
  __shared__ float c_sh[8];
  __shared__ u64 sched_last;       // block-local detect timestamp
  __shared__ u64 sched_pe;         // period EMA (shader cycles)

  const int tid = threadIdx.x, bid = blockIdx.x;
  const int w = tid >> 6, g = tid & 63;

  // W_h into registers (bf16 packed pairs): wave w rows {2w, 2w+1}
  const int lr0 = 2 * w;
  const int gate = lr0 >> 3, jj0 = lr0 & 7;
  const float* Wg = (gate == 0) ? Wf : (gate == 1) ? Wi : (gate == 2) ? Wc : Wo;
  const float* W0 = Wg + (size_t)(bid * 8 + jj0) * 2560 + 512;
  const float* W1 = W0 + 2560;
  uint4 wa[4], wb[4];
#pragma unroll
  for (int i = 0; i < 4; ++i) {
    int col = (i * 64 + g) * 8;
    float4 x0 = *(const float4*)(W0 + col);
    float4 x1 = *(const float4*)(W0 + col + 4);
    wa[i] = make_uint4(pk2(x0.x, x0.y), pk2(x0.z, x0.w), pk2(x1.x, x1.y), pk2(x1.z, x1.w));
    float4 y0 = *(const float4*)(W1 + col);
    float4 y1 = *(const float4*)(W1 + col + 4);
    wb[i] = make_uint4(pk2(y0.x, y0.y), pk2(y0.z, y0.w), pk2(y1.x, y1.y), pk2(y1.z, y1.w));
  }

  // stage G_x slice + seq, zero h/c
  gxsh4[tid] = ((const uint4*)(gxg + (size_t)bid * 8192))[tid];
  {
    int4 v0 = ((const int4*)seq)[tid];
    int4 v1 = ((const int4*)seq)[tid + 1024];
    seq_sh[4 * tid + 0] = (uchar)v0.x; seq_sh[4 * tid + 1] = (uchar)v0.y;
    seq_sh[4 * tid + 2] = (uchar)v0.z; seq_sh[4 * tid + 3] = (uchar)v0.w;
    seq_sh[4096 + 4 * tid + 0] = (uchar)v1.x; seq_sh[4096 + 4 * tid + 1] = (uchar)v1.y;
    seq_sh[4096 + 4 * tid + 2] = (uchar)v1.z; seq_sh[4096 + 4 * tid + 3] = (uchar)v1.w;
  }
  if (tid < 256) hsh4[tid] = make_uint4(0u, 0u, 0u, 0u);
  if (tid < 8)  c_sh[tid] = 0.f;
  if (tid == 0) { sched_last = clock64(); sched_pe = 0ull; }
  __syncthreads();

  const ushort* gx_sh = (const ushort*)gxsh4;
  uint* hsh_dw = (uint*)hsh4;

  for (int t = 0; t < TSTEPS; ++t) {
    // ---- timing update (tid 0): measure block step period, EMA(1/4) ----
    // Written here (before sync#1); consumed at the poll site (after sync#1).
    if (tid == 0) {
      u64 now = clock64();
      u64 raw = now - sched_last;
      sched_last = now;
      u64 pe = sched_pe;
      sched_pe = pe - (pe >> 2) + (raw >> 2);
    }

    // ---- phase A: partial dots over h_{t-1} (all 16 waves) ----
    float a0 = 0.f, a1 = 0.f;
#pragma unroll
    for (int i = 0; i < 4; ++i) {
      uint4 hv = hsh4[i * 64 + g];
      a0 = dot2bf(wa[i].x, hv.x, a0); a0 = dot2bf(wa[i].y, hv.y, a0);
      a0 = dot2bf(wa[i].z, hv.z, a0); a0 = dot2bf(wa[i].w, hv.w, a0);
      a1 = dot2bf(wb[i].x, hv.x, a1); a1 = dot2bf(wb[i].y, hv.y, a1);
      a1 = dot2bf(wb[i].z, hv.z, a1); a1 = dot2bf(wb[i].w, hv.w, a1);
    }
    float s0 = __shfl_xor(a0, 32);
    float s1 = __shfl_xor(a1, 32);
    float a = (g < 32) ? (a0 + s0) : (a1 + s1);
    a += __shfl_xor(a, 16); a += __shfl_xor(a, 8);
    a += __shfl_xor(a, 4);  a += __shfl_xor(a, 2); a += __shfl_xor(a, 1);
    if ((g & 31) == 0) g_sh[lr0 + (g >> 5)] = a;
    __syncthreads();   // #1: g_sh ready

    // ---- gates: wave 0, lanes 0..7 (h element j = g) ----
    if (w == 0 && g < 8) {
      const int ch = (int)seq_sh[t];
      const ushort* gx = gx_sh + ch * 32;
      float vf = g_sh[g]      + bf2f(gx[g]);
      float vi = g_sh[8 + g]  + bf2f(gx[8 + g]);
      float vc = g_sh[16 + g] + bf2f(gx[16 + g]);
      float vo = g_sh[24 + g] + bf2f(gx[24 + g]);
      float f_ = sigm(vf), i_ = sigm(vi), ct_ = tanh_f(vc), o_ = sigm(vo);
      float cn = f_ * c_sh[g] + i_ * ct_;
      c_sh[g] = cn;
      float h = o_ * tanh_f(cn);
      uint hb = (uint)f2bf(h);
      uint nb = __shfl_down(hb, 1);
      if ((g & 1) == 0) {
        uint dw = hb | (nb << 16);
        int di = bid * 4 + (g >> 1);
        u64 v = (u64)dw | ((u64)(uint)(t + 1) << 32);
        __hip_atomic_store(hbuf + (size_t)(t & 1) * 1024 + di, v,
                           __ATOMIC_RELAXED, __HIP_MEMORY_SCOPE_AGENT);
        __builtin_nontemporal_store(dw, hist + (size_t)t * 1024 + di);
      }
      if (t == TSTEPS - 1) { out_h[bid * 8 + g] = h; out_c[bid * 8 + g] = cn; }
    }

    // ---- exchange: calibrated rendezvous, then per-thread own-slot poll ----
    if (t < TSTEPS - 1) {
      {
        u64 pe = sched_pe;           // after sync#1: tid0's update visible
        if (pe > CAL_MINPE) {
          u64 tgt = sched_last + pe - CAL_MARGIN;
          while ((i64)(tgt - clock64()) > 0) __builtin_amdgcn_s_sleep(2);
        }
      }
      const u64 want = (u64)(uint)(t + 1);
      const u64* slot = hbuf + (size_t)(t & 1) * 1024 + tid;
      u64 v;
      do {
        v = __hip_atomic_load(slot, __ATOMIC_RELAXED, __HIP_MEMORY_SCOPE_AGENT);
      } while ((v >> 32) != want);
      hsh_dw[tid] = (uint)v;
    }
    __syncthreads();   // #2: h_t staged in LDS
  }
}

// ---------- kernel C: y = hist @ W_y^T + b_y ----------
__global__ __launch_bounds__(256) void y_kernel(
    const ushort* __restrict__ hist,
    const ushort* __restrict__ Wyb,
    const float* __restrict__ by,
    float* __restrict__ y)
{
  __shared__ uint4 hsh4[4096];   // 16 x 2048 bf16 = 64 KB
  const int tid = threadIdx.x, bid = blockIdx.x;
  const int t0 = bid * 16;
  const uint4* src = (const uint4*)(hist + (size_t)t0 * 2048);
  for (int i = tid; i < 4096; i += 256) hsh4[i] = src[i];
  __syncthreads();
  const int a = tid >> 6, b = tid & 63;
  const int n0 = b * 4;
  float acc[4][4];
#pragma unroll
  for (int i = 0; i < 4; ++i)
#pragma unroll
    for (int j = 0; j < 4; ++j) acc[i][j] = 0.f;
  const uint4* wy = (const uint4*)Wyb;
  for (int k8 = 0; k8 < 256; ++k8) {
    uint4 hv[4];
#pragma unroll
    for (int ti = 0; ti < 4; ++ti) hv[ti] = hsh4[(a + ti * 4) * 256 + k8];
#pragma unroll
    for (int nj = 0; nj < 4; ++nj) {
      uint4 wv = wy[(size_t)(n0 + nj) * 256 + k8];
#pragma unroll
      for (int ti = 0; ti < 4; ++ti) {
        acc[ti][nj] = dot2bf(hv[ti].x, wv.x, acc[ti][nj]);
        acc[ti][nj] = dot2bf(hv[ti].y, wv.y, acc[ti][nj]);
        acc[ti][nj] = dot2bf(hv[ti].z, wv.z, acc[ti][nj]);
        acc[ti][nj] = dot2bf(hv[ti].w, wv.w, acc[ti][nj]);
      }
    }
  }
  float4 bv = *(const float4*)(by + n0);
#pragma unroll
  for (int ti = 0; ti < 4; ++ti) {
    int t = t0 + a + ti * 4;
    float4 o;
    o.x = acc[ti][0] + bv.x; o.y = acc[ti][1] + bv.y;
    o.z = acc[ti][2] + bv.z; o.w = acc[ti][3] + bv.w;
    *(float4*)(y + (size_t)t * 256 + n0) = o;
  }
}

// ---------- launcher ----------
extern "C" void kernel_launch(void* const* d_in, const int* in_sizes, int n_in,
                              void* d_out, int out_size, void* d_ws, size_t ws_size,
                              hipStream_t stream)
{
  const int*   seq = (const int*)d_in[0];
  const float* emb = (const float*)d_in[1];
  const float* Wf  = (const float*)d_in[2];
  const float* bf_ = (const float*)d_in[3];
  const float* Wi  = (const float*)d_in[4];
  const float* bi_ = (const float*)d_in[5];
  const float* Wo  = (const float*)d_in[6];
  const float* bo_ = (const float*)d_in[7];
  const float* Wc  = (const float*)d_in[8];
  const float* bc_ = (const float*)d_in[9];
  const float* Wy  = (const float*)d_in[10];
  const float* by  = (const float*)d_in[11];

  // ws layout
  const size_t OFF_GXG  = 0;                    // 4 MB   (256*256*32 bf16)
  const size_t OFF_HIST = 4194304;              // 32 MB  (8192*2048 bf16)
  const size_t OFF_HBUF = OFF_HIST + 33554432;  // 16 KB  (2*1024 u64 slots)
  const size_t OFF_WYB  = OFF_HBUF + 16384;     // 1 MB
  const size_t NEEDED   = OFF_WYB + 1048576;
  if (ws_size < NEEDED) return;

  char* ws = (char*)d_ws;
  ushort* gxg  = (ushort*)(ws + OFF_GXG);
  ushort* hist = (ushort*)(ws + OFF_HIST);
  u64*    hbuf = (u64*)   (ws + OFF_HBUF);
  ushort* Wyb  = (ushort*)(ws + OFF_WYB);

  float* yout  = (float*)d_out;
  float* out_h = yout + (size_t)TSTEPS * 256;
  float* out_c = out_h + HIDDEN;

  hipLaunchKernelGGL(gx_kernel, dim3(256), dim3(256), 0, stream,
                     emb, Wf, bf_, Wi, bi_, Wc, bc_, Wo, bo_, gxg);
  hipLaunchKernelGGL(wyb_kernel, dim3(512), dim3(256), 0, stream, Wy, Wyb);
  hipLaunchKernelGGL(lstm_kernel, dim3(256), dim3(1024), 0, stream,
                     seq, Wf, Wi, Wc, Wo, gxg, (uint*)hist, hbuf,
                     out_h, out_c);
  hipLaunchKernelGGL(y_kernel, dim3(512), dim3(256), 0, stream,
                     hist, Wyb, by, yout);
}